// Round 12
// baseline (52.829 us; speedup 1.0000x reference)
//
#include <hip/hip_runtime.h>
#include <math.h>

#define N 128
#define HID 512
#define NH (N * HID)                 // 65536
#define SNH ((size_t)N * NH)         // 8388608 elements per s
#define NPAIRS (N * (N + 1) / 2)     // 8256

// workspace layout (float offsets)
#define OFF_PSC 0                    // PScol [2][16][128][512]
#define OFF_PSR 2097152              // PSrow [2][16][128][512]
#define OFF_DG  4194304              // Dg    [2][128][512]
#define OFF_XR  4325376              // Xr    [2][128][512]
#define OFF_YC  4456448              // Yc    [2][128][512]
#define OFF_SV  4587520              // Sv    [2][512]
#define OFF_DB  4588544              // Db    [2][512]

typedef float vf4 __attribute__((ext_vector_type(4)));
union F4 { vf4 v; float f[4]; };

// ---------------------------------------------------------------------------
// K1: fully-contiguous dense-cube partial sums.
// Block = (s, ag, bg): 2*16*16 = 512 blocks. Block owns 8a x 8b x FULL H:
// per a, its span x[s][a][bg*8..+8][:] is 16 KB contiguous (8 whole 2KB lines).
//   PScol[s][ag][b][h] = sum_{a in ag} x[s][a][b][h]   (register acc, direct)
//   PSrow[s][bg][a][h] = sum_{b in bg} x[s][a][b][h]   (LDS reduce, 1 sync)
//   Dg[s][a][h]        = x[s][a][a][h]                 (in-loop capture, ag==bg)
// 256 threads = f(128 h-float4) x bh(2, 4 b's each).
// ---------------------------------------------------------------------------
__global__ __launch_bounds__(256, 8)
void schur_p1(const float* __restrict__ x, float* __restrict__ PScol,
              float* __restrict__ PSrow, float* __restrict__ Dg) {
    const int u   = blockIdx.x;           // 0..511
    const int bg  = u & 15;
    const int ag  = (u >> 4) & 15;
    const int s   = u >> 8;               // 0..1
    const int tid = threadIdx.x;          // 0..255
    const int f   = tid & 127;            // h float4 index
    const int bh  = tid >> 7;             // 0..1
    const int hoff = f * 4;
    const int b0   = bg * 8 + bh * 4;

    const float* xs   = x + (size_t)s * SNH;
    const float* base = xs + (size_t)(ag * 8) * NH + b0 * HID + hoff;
    const bool diag = (ag == bg);

    __shared__ F4 rowall[8][2][128];      // 8 KiB

    F4 c0, c1, c2, c3;
    c0.v = (vf4)(0.f); c1.v = (vf4)(0.f); c2.v = (vf4)(0.f); c3.v = (vf4)(0.f);

    #pragma unroll
    for (int ai = 0; ai < 8; ++ai) {      // fully unrolled: ai compile-time
        const float* p = base + (size_t)ai * NH;
        F4 v0; v0.v = *reinterpret_cast<const vf4*>(p);
        F4 v1; v1.v = *reinterpret_cast<const vf4*>(p + HID);
        F4 v2; v2.v = *reinterpret_cast<const vf4*>(p + 2 * HID);
        F4 v3; v3.v = *reinterpret_cast<const vf4*>(p + 3 * HID);
        c0.v += v0.v; c1.v += v1.v; c2.v += v2.v; c3.v += v3.v;
        F4 rs; rs.v = (v0.v + v1.v) + (v2.v + v3.v);
        rowall[ai][bh][f] = rs;
        if (diag && (ai >> 2) == bh) {
            // b-local (bh*4 + j) == ai  ->  j = ai & 3 (compile-time)
            const int a = ag * 8 + ai;
            F4 dv;
            if ((ai & 3) == 0)      dv = v0;
            else if ((ai & 3) == 1) dv = v1;
            else if ((ai & 3) == 2) dv = v2;
            else                    dv = v3;
            *reinterpret_cast<vf4*>(Dg + (((size_t)s * N + a) * HID + hoff)) = dv.v;
        }
    }
    __syncthreads();

    // PScol: thread's 4 b-columns, summed over the block's 8 a's
    *reinterpret_cast<vf4*>(PScol + ((((size_t)s * 16 + ag) * N + b0 + 0) * HID + hoff)) = c0.v;
    *reinterpret_cast<vf4*>(PScol + ((((size_t)s * 16 + ag) * N + b0 + 1) * HID + hoff)) = c1.v;
    *reinterpret_cast<vf4*>(PScol + ((((size_t)s * 16 + ag) * N + b0 + 2) * HID + hoff)) = c2.v;
    *reinterpret_cast<vf4*>(PScol + ((((size_t)s * 16 + ag) * N + b0 + 3) * HID + hoff)) = c3.v;

    // PSrow: 8a x 128f outputs; thread handles a = bh, bh+2, bh+4, bh+6
    #pragma unroll
    for (int k = 0; k < 4; ++k) {
        const int ai = bh + 2 * k;
        F4 t; t.v = rowall[ai][0][f].v + rowall[ai][1][f].v;
        *reinterpret_cast<vf4*>(PSrow +
            ((((size_t)s * 16 + bg) * N + ag * 8 + ai) * HID + hoff)) = t.v;
    }
}

// ---------------------------------------------------------------------------
// K2: fold PScol(16)/PSrow(16)/Dg -> per-(s,h) stats -> Xr, Yc, Sv, Db.
// 32 blocks x 512 threads.
// ---------------------------------------------------------------------------
__global__ __launch_bounds__(512)
void schur_p2(const float* __restrict__ PScol, const float* __restrict__ PSrow,
              const float* __restrict__ Dg,
              float* __restrict__ Xr, float* __restrict__ Yc,
              float* __restrict__ Sv, float* __restrict__ Db) {
    const int bi = blockIdx.x;            // 0..31
    const int s  = bi >> 4;
    const int hc = bi & 15;
    const int t  = threadIdx.x;
    const int iq = t >> 5;                // 0..15
    const int hl = t & 31;
    const int h  = hc * 32 + hl;

    float sa8[8], sb8[8], d8[8];
    float T = 0.f, D = 0.f;
    #pragma unroll
    for (int k = 0; k < 8; ++k) {
        const int i = iq + k * 16;
        float sa = 0.f, sb = 0.f;
        #pragma unroll
        for (int gg = 0; gg < 16; ++gg)
            sa += PScol[(((size_t)s * 16 + gg) * N + i) * HID + h];
        #pragma unroll
        for (int qq = 0; qq < 16; ++qq)
            sb += PSrow[(((size_t)s * 16 + qq) * N + i) * HID + h];
        const float d = Dg[((size_t)s * N + i) * HID + h];
        sa8[k] = sa; sb8[k] = sb; d8[k] = d;
        T += sa; D += d;
    }

    __shared__ float redT[16][32];
    __shared__ float redD[16][32];
    __shared__ float shS[32];
    redT[iq][hl] = T;
    redD[iq][hl] = D;
    __syncthreads();
    if (iq == 0) {
        float Tt = 0.f, Dd = 0.f;
        #pragma unroll
        for (int q = 0; q < 16; ++q) { Tt += redT[q][hl]; Dd += redD[q][hl]; }
        const float sh   = (Tt - Dd) * (1.0f / 16256.0f);   // /(n(n-1))
        const float dbar = Dd * (1.0f / 128.0f);
        Sv[s * HID + h] = sh;
        Db[s * HID + h] = dbar;
        shS[hl] = sh;
    }
    __syncthreads();

    const float sh    = shS[hl];
    const float k127s = 127.0f * sh;
    const float inv   = 1.0f / 16128.0f;  // 1/(n(n-2))
    const size_t base = (size_t)s * N * HID;
    #pragma unroll
    for (int k = 0; k < 8; ++k) {
        const int i = iq + k * 16;
        const float d = d8[k];
        const float r = sa8[k] - d - k127s;
        const float c = sb8[k] - d - k127s;
        Xr[base + (size_t)i * HID + h] = (127.0f * r + c) * inv;
        Yc[base + (size_t)i * HID + h] = (127.0f * c + r) * inv;
    }
}

// ---------------------------------------------------------------------------
// K3: output over triangular pairs (R5 p3, verbatim; proven best).
// 2064 blocks x 256 threads, 8 consecutive pairs per block; NT stores.
// ---------------------------------------------------------------------------
__global__ __launch_bounds__(256)
void schur_p3(const float* __restrict__ x, const float* __restrict__ w,
              const float* __restrict__ iso,
              const float* __restrict__ Xr, const float* __restrict__ Yc,
              const float* __restrict__ Sv, const float* __restrict__ Db,
              float* __restrict__ out) {
    const int t  = threadIdx.x;
    const int k  = t >> 7;                // pair slot 0/1
    const int ht = t & 127;
    const int hoff = ht * 4;

    float c[7];
    #pragma unroll
    for (int j = 0; j < 7; ++j) {
        float acc = 0.f;
        #pragma unroll
        for (int i = 0; i < 7; ++i) acc += w[i * 7 + j] * iso[i * 7 + j];
        c[j] = acc;
    }
    const float c1 = c[0], c2 = c[1], c3 = c[2], c4 = c[3], c5 = c[4];
    const float al = 0.5f * (c[5] + c[6]);
    const float be = 0.5f * (c[5] - c[6]);

    const int pg0 = blockIdx.x * 8;

    #define TRI_OFF(aa) ((aa) * N - (((aa) * ((aa) - 1)) >> 1))
    #pragma unroll
    for (int it = 0; it < 4; ++it) {
        const int pg = pg0 + it * 2 + k;      // global pair id, < 16512
        const int s  = (pg >= NPAIRS) ? 1 : 0;
        const int p  = pg - s * NPAIRS;

        int a = (int)((257.0f - sqrtf((float)(66049 - 8 * p))) * 0.5f);
        if (a < 0) a = 0;
        if (a > N - 1) a = N - 1;
        while (a > 0 && TRI_OFF(a) > p) --a;
        while (TRI_OFF(a + 1) <= p) ++a;
        const int b = a + (p - TRI_OFF(a));

        const size_t sbase    = (size_t)s * SNH;
        const size_t statbase = (size_t)s * N * HID;

        if (a == b) {
            F4 v;  v.v  = *reinterpret_cast<const vf4*>(x + sbase + ((size_t)a * N + a) * HID + hoff);
            F4 db; db.v = *reinterpret_cast<const vf4*>(Db + (size_t)s * HID + hoff);
            F4 o;
            #pragma unroll
            for (int j = 0; j < 4; ++j)
                o.f[j] = c1 * db.f[j] + c2 * (v.f[j] - db.f[j]);
            __builtin_nontemporal_store(o.v,
                reinterpret_cast<vf4*>(out + sbase + ((size_t)a * N + a) * HID + hoff));
            continue;
        }

        F4 va;  va.v  = *reinterpret_cast<const vf4*>(x + sbase + ((size_t)a * N + b) * HID + hoff);
        F4 vb;  vb.v  = *reinterpret_cast<const vf4*>(x + sbase + ((size_t)b * N + a) * HID + hoff);
        F4 xra; xra.v = *reinterpret_cast<const vf4*>(Xr + statbase + (size_t)a * HID + hoff);
        F4 xrb; xrb.v = *reinterpret_cast<const vf4*>(Xr + statbase + (size_t)b * HID + hoff);
        F4 yca; yca.v = *reinterpret_cast<const vf4*>(Yc + statbase + (size_t)a * HID + hoff);
        F4 ycb; ycb.v = *reinterpret_cast<const vf4*>(Yc + statbase + (size_t)b * HID + hoff);
        F4 sh;  sh.v  = *reinterpret_cast<const vf4*>(Sv + (size_t)s * HID + hoff);

        F4 oab, oba;
        #pragma unroll
        for (int j = 0; j < 4; ++j) {
            const float U = va.f[j] - sh.f[j] - xrb.f[j] - yca.f[j];
            const float V = vb.f[j] - sh.f[j] - xra.f[j] - ycb.f[j];
            oab.f[j] = c3 * sh.f[j] + c4 * xrb.f[j] + c5 * yca.f[j] + al * U + be * V;
            oba.f[j] = c3 * sh.f[j] + c4 * xra.f[j] + c5 * ycb.f[j] + al * V + be * U;
        }
        __builtin_nontemporal_store(oab.v,
            reinterpret_cast<vf4*>(out + sbase + ((size_t)a * N + b) * HID + hoff));
        __builtin_nontemporal_store(oba.v,
            reinterpret_cast<vf4*>(out + sbase + ((size_t)b * N + a) * HID + hoff));
    }
}

extern "C" void kernel_launch(void* const* d_in, const int* in_sizes, int n_in,
                              void* d_out, int out_size, void* d_ws, size_t ws_size,
                              hipStream_t stream) {
    const float* x   = (const float*)d_in[0];
    const float* w   = (const float*)d_in[1];
    const float* iso = (const float*)d_in[2];
    float* out = (float*)d_out;
    float* ws  = (float*)d_ws;

    float* PScol = ws + OFF_PSC;
    float* PSrow = ws + OFF_PSR;
    float* Dg    = ws + OFF_DG;
    float* Xr    = ws + OFF_XR;
    float* Yc    = ws + OFF_YC;
    float* Sv    = ws + OFF_SV;
    float* Db    = ws + OFF_DB;

    schur_p1<<<512, 256, 0, stream>>>(x, PScol, PSrow, Dg);
    schur_p2<<<32, 512, 0, stream>>>(PScol, PSrow, Dg, Xr, Yc, Sv, Db);
    schur_p3<<<2064, 256, 0, stream>>>(x, w, iso, Xr, Yc, Sv, Db, out);
}

// Round 13
// 45.001 us; speedup vs baseline: 1.1740x; 1.1740x over previous
//
#include <hip/hip_runtime.h>
#include <math.h>

#define N 128
#define HID 512
#define NH (N * HID)                 // 65536
#define SNH ((size_t)N * NH)         // 8388608 elements per s
#define NPAIRS (N * (N + 1) / 2)     // 8256

// workspace layout (float offsets) — same as R11
#define OFF_PSC 0                    // PScol [2][8][128][512]
#define OFF_PSR 4194304              // PSrow [2][4][128][512]
#define OFF_DG  4718592              // Dg    [2][128][512]
#define OFF_XR  4849664              // Xr    [2][128][512]
#define OFF_YC  4980736              // Yc    [2][128][512]
#define OFF_SV  5111808              // Sv    [2][512]
#define OFF_DB  5112832              // Db    [2][512]

typedef float vf4 __attribute__((ext_vector_type(4)));
union F4 { vf4 v; float f[4]; };

// ---------------------------------------------------------------------------
// K1: stride-free dense-cube partial sums (R11 p1, VERBATIM — proven).
// Block = (s, g=a-octet-of-16, bq=b-quarter, hq=h-quarter): 2*8*4*4 = 256.
// ---------------------------------------------------------------------------
__global__ __launch_bounds__(512)
void schur_p1(const float* __restrict__ x, float* __restrict__ PScol,
              float* __restrict__ PSrow, float* __restrict__ Dg) {
    const int u  = blockIdx.x;            // 0..255
    const int hq = u & 3;
    const int bq = (u >> 2) & 3;
    const int g  = (u >> 4) & 7;
    const int s  = u >> 7;                // 0..1
    const int tid = threadIdx.x;
    const int f   = tid & 31;             // float4 within h-quarter
    const int bg  = tid >> 5;             // 0..15, 2 b's each
    const int b0  = bq * 32 + bg * 2;
    const int hoff = hq * 128 + f * 4;

    const float* xs   = x + (size_t)s * SNH;
    const float* base = xs + (size_t)(g * 16) * NH + b0 * HID + hoff;

    __shared__ F4 rowred[8][16][32];      // 64 KiB

    F4 acc0, acc1;
    acc0.v = (vf4)(0.f); acc1.v = (vf4)(0.f);

    #pragma unroll
    for (int c = 0; c < 2; ++c) {
        #pragma unroll
        for (int al = 0; al < 8; ++al) {
            const float* p = base + (size_t)(c * 8 + al) * NH;
            F4 v0; v0.v = *reinterpret_cast<const vf4*>(p);
            F4 v1; v1.v = *reinterpret_cast<const vf4*>(p + HID);
            acc0.v += v0.v;
            acc1.v += v1.v;
            F4 rs; rs.v = v0.v + v1.v;
            rowred[al][bg][f] = rs;
        }
        __syncthreads();
        if (tid < 256) {
            const int ar = tid >> 5;      // 0..7
            const int f2 = tid & 31;
            F4 t; t.v = (vf4)(0.f);
            #pragma unroll
            for (int k = 0; k < 16; ++k) t.v += rowred[ar][k][f2].v;
            const int a = g * 16 + c * 8 + ar;
            *reinterpret_cast<vf4*>(PSrow +
                ((((size_t)s * 4 + bq) * N + a) * HID + hq * 128 + f2 * 4)) = t.v;
        }
        __syncthreads();
    }

    *reinterpret_cast<vf4*>(PScol +
        ((((size_t)s * 8 + g) * N + b0) * HID + hoff)) = acc0.v;
    *reinterpret_cast<vf4*>(PScol +
        ((((size_t)s * 8 + g) * N + b0 + 1) * HID + hoff)) = acc1.v;

    if (bq == (g >> 1)) {
        const int ar = tid >> 5;          // 0..15
        const int f2 = tid & 31;
        const int a  = g * 16 + ar;
        const vf4 dv = *reinterpret_cast<const vf4*>(
            xs + (size_t)a * NH + a * HID + hq * 128 + f2 * 4);
        *reinterpret_cast<vf4*>(Dg +
            (((size_t)s * N + a) * HID + hq * 128 + f2 * 4)) = dv;
    }
}

// ---------------------------------------------------------------------------
// K2: VECTORIZED fold PScol(8)/PSrow(4)/Dg -> stats -> Xr, Yc, Sv, Db.
// 32 blocks x 256 threads; thread = (iq in [0,32), hf in [0,8)) handling one
// float4 of h and 4 i-values; all loads vf4 (was 104 scalar loads/thread).
// ---------------------------------------------------------------------------
__global__ __launch_bounds__(256)
void schur_p2(const float* __restrict__ PScol, const float* __restrict__ PSrow,
              const float* __restrict__ Dg,
              float* __restrict__ Xr, float* __restrict__ Yc,
              float* __restrict__ Sv, float* __restrict__ Db) {
    const int bi = blockIdx.x;            // 0..31
    const int s  = bi >> 4;
    const int hc = bi & 15;               // 8 float4 per chunk
    const int tid = threadIdx.x;          // 0..255
    const int iq = tid >> 3;              // 0..31
    const int hf = tid & 7;
    const int h  = (hc * 8 + hf) * 4;     // float offset in [0,512)

    F4 sa[4], sb[4], dg[4];
    F4 T, D; T.v = (vf4)(0.f); D.v = (vf4)(0.f);
    #pragma unroll
    for (int k = 0; k < 4; ++k) {
        const int i = iq + 32 * k;
        F4 acc; acc.v = (vf4)(0.f);
        #pragma unroll
        for (int gg = 0; gg < 8; ++gg)
            acc.v += reinterpret_cast<const F4*>(
                PScol + (((size_t)s * 8 + gg) * N + i) * HID + h)->v;
        sa[k] = acc; T.v += acc.v;
        F4 accb; accb.v = (vf4)(0.f);
        #pragma unroll
        for (int qq = 0; qq < 4; ++qq)
            accb.v += reinterpret_cast<const F4*>(
                PSrow + (((size_t)s * 4 + qq) * N + i) * HID + h)->v;
        sb[k] = accb;
        dg[k].v = reinterpret_cast<const F4*>(
            Dg + ((size_t)s * N + i) * HID + h)->v;
        D.v += dg[k].v;
    }

    __shared__ F4 redT[32][8];
    __shared__ F4 redD[32][8];
    __shared__ F4 shS[8];
    redT[iq][hf] = T;
    redD[iq][hf] = D;
    __syncthreads();
    if (iq == 0) {
        F4 Tt, Dd; Tt.v = (vf4)(0.f); Dd.v = (vf4)(0.f);
        #pragma unroll
        for (int q = 0; q < 32; ++q) { Tt.v += redT[q][hf].v; Dd.v += redD[q][hf].v; }
        F4 sh, db_;
        sh.v  = (Tt.v - Dd.v) * (1.0f / 16256.0f);   // /(n(n-1))
        db_.v = Dd.v * (1.0f / 128.0f);
        *reinterpret_cast<vf4*>(Sv + s * HID + h) = sh.v;
        *reinterpret_cast<vf4*>(Db + s * HID + h) = db_.v;
        shS[hf] = sh;
    }
    __syncthreads();

    const F4 sh = shS[hf];
    const float inv = 1.0f / 16128.0f;    // 1/(n(n-2))
    const size_t base = (size_t)s * N * HID;
    #pragma unroll
    for (int k = 0; k < 4; ++k) {
        const int i = iq + 32 * k;
        F4 r, c, xr, yc;
        r.v = sa[k].v - dg[k].v - 127.0f * sh.v;
        c.v = sb[k].v - dg[k].v - 127.0f * sh.v;
        xr.v = (127.0f * r.v + c.v) * inv;
        yc.v = (127.0f * c.v + r.v) * inv;
        *reinterpret_cast<vf4*>(Xr + base + (size_t)i * HID + h) = xr.v;
        *reinterpret_cast<vf4*>(Yc + base + (size_t)i * HID + h) = yc.v;
    }
}

// ---------------------------------------------------------------------------
// K3: output over triangular pairs (R5/R11 p3) + XCD-aware bijective swizzle:
// 2064 blocks = 8 XCDs x 258 contiguous pair-chunks each (T1, guide §5.5).
// ---------------------------------------------------------------------------
__global__ __launch_bounds__(256)
void schur_p3(const float* __restrict__ x, const float* __restrict__ w,
              const float* __restrict__ iso,
              const float* __restrict__ Xr, const float* __restrict__ Yc,
              const float* __restrict__ Sv, const float* __restrict__ Db,
              float* __restrict__ out) {
    const int t  = threadIdx.x;
    const int k  = t >> 7;                // pair slot 0/1
    const int ht = t & 127;
    const int hoff = ht * 4;

    float c[7];
    #pragma unroll
    for (int j = 0; j < 7; ++j) {
        float acc = 0.f;
        #pragma unroll
        for (int i = 0; i < 7; ++i) acc += w[i * 7 + j] * iso[i * 7 + j];
        c[j] = acc;
    }
    const float c1 = c[0], c2 = c[1], c3 = c[2], c4 = c[3], c5 = c[4];
    const float al = 0.5f * (c[5] + c[6]);
    const float be = 0.5f * (c[5] - c[6]);

    // bijective XCD swizzle: 2064 = 8 * 258
    const int bid = blockIdx.x;
    const int swz = (bid & 7) * 258 + (bid >> 3);
    const int pg0 = swz * 8;

    #define TRI_OFF(aa) ((aa) * N - (((aa) * ((aa) - 1)) >> 1))
    #pragma unroll
    for (int it = 0; it < 4; ++it) {
        const int pg = pg0 + it * 2 + k;      // global pair id, < 16512
        const int s  = (pg >= NPAIRS) ? 1 : 0;
        const int p  = pg - s * NPAIRS;

        int a = (int)((257.0f - sqrtf((float)(66049 - 8 * p))) * 0.5f);
        if (a < 0) a = 0;
        if (a > N - 1) a = N - 1;
        while (a > 0 && TRI_OFF(a) > p) --a;
        while (TRI_OFF(a + 1) <= p) ++a;
        const int b = a + (p - TRI_OFF(a));

        const size_t sbase    = (size_t)s * SNH;
        const size_t statbase = (size_t)s * N * HID;

        if (a == b) {
            F4 v;  v.v  = *reinterpret_cast<const vf4*>(x + sbase + ((size_t)a * N + a) * HID + hoff);
            F4 db; db.v = *reinterpret_cast<const vf4*>(Db + (size_t)s * HID + hoff);
            F4 o;
            #pragma unroll
            for (int j = 0; j < 4; ++j)
                o.f[j] = c1 * db.f[j] + c2 * (v.f[j] - db.f[j]);
            __builtin_nontemporal_store(o.v,
                reinterpret_cast<vf4*>(out + sbase + ((size_t)a * N + a) * HID + hoff));
            continue;
        }

        F4 va;  va.v  = *reinterpret_cast<const vf4*>(x + sbase + ((size_t)a * N + b) * HID + hoff);
        F4 vb;  vb.v  = *reinterpret_cast<const vf4*>(x + sbase + ((size_t)b * N + a) * HID + hoff);
        F4 xra; xra.v = *reinterpret_cast<const vf4*>(Xr + statbase + (size_t)a * HID + hoff);
        F4 xrb; xrb.v = *reinterpret_cast<const vf4*>(Xr + statbase + (size_t)b * HID + hoff);
        F4 yca; yca.v = *reinterpret_cast<const vf4*>(Yc + statbase + (size_t)a * HID + hoff);
        F4 ycb; ycb.v = *reinterpret_cast<const vf4*>(Yc + statbase + (size_t)b * HID + hoff);
        F4 sh;  sh.v  = *reinterpret_cast<const vf4*>(Sv + (size_t)s * HID + hoff);

        F4 oab, oba;
        #pragma unroll
        for (int j = 0; j < 4; ++j) {
            const float U = va.f[j] - sh.f[j] - xrb.f[j] - yca.f[j];
            const float V = vb.f[j] - sh.f[j] - xra.f[j] - ycb.f[j];
            oab.f[j] = c3 * sh.f[j] + c4 * xrb.f[j] + c5 * yca.f[j] + al * U + be * V;
            oba.f[j] = c3 * sh.f[j] + c4 * xra.f[j] + c5 * ycb.f[j] + al * V + be * U;
        }
        __builtin_nontemporal_store(oab.v,
            reinterpret_cast<vf4*>(out + sbase + ((size_t)a * N + b) * HID + hoff));
        __builtin_nontemporal_store(oba.v,
            reinterpret_cast<vf4*>(out + sbase + ((size_t)b * N + a) * HID + hoff));
    }
}

extern "C" void kernel_launch(void* const* d_in, const int* in_sizes, int n_in,
                              void* d_out, int out_size, void* d_ws, size_t ws_size,
                              hipStream_t stream) {
    const float* x   = (const float*)d_in[0];
    const float* w   = (const float*)d_in[1];
    const float* iso = (const float*)d_in[2];
    float* out = (float*)d_out;
    float* ws  = (float*)d_ws;

    float* PScol = ws + OFF_PSC;
    float* PSrow = ws + OFF_PSR;
    float* Dg    = ws + OFF_DG;
    float* Xr    = ws + OFF_XR;
    float* Yc    = ws + OFF_YC;
    float* Sv    = ws + OFF_SV;
    float* Db    = ws + OFF_DB;

    schur_p1<<<256, 512, 0, stream>>>(x, PScol, PSrow, Dg);
    schur_p2<<<32, 256, 0, stream>>>(PScol, PSrow, Dg, Xr, Yc, Sv, Db);
    schur_p3<<<2064, 256, 0, stream>>>(x, w, iso, Xr, Yc, Sv, Db, out);
}